// Round 1
// baseline (12193.527 us; speedup 1.0000x reference)
//
#include <hip/hip_runtime.h>

// ---------------------------------------------------------------------------
// Graph multi-head attention conv, fp32 baseline.
//   N=100000 nodes, E=1600000 edges, H=8 heads, C=16, DIM=128, EDGE_DIM=32
// Stages:
//   1) qkv_gemm_kernel : q/k/v = x @ W{q,k,v}^T     (tiled fp32 SGEMM)
//   2) edge_score_kernel: ex[e,h]=exp(q[dst]·k[src]/4 + eattr·We[h]);
//                         denom[dst,h] += ex        (atomic)
//   3) edge_out_kernel : out[dst,h,:] += (ex/denom[dst,h]) * v[src,h,:] (atomic)
// Segment-max subtraction is skipped: alpha is invariant to it and scores
// are O(10) -- no fp32 exp overflow risk.
// ---------------------------------------------------------------------------

__global__ __launch_bounds__(256) void qkv_gemm_kernel(
    const float* __restrict__ x,
    const float* __restrict__ Wq,
    const float* __restrict__ Wk,
    const float* __restrict__ Wv,
    float* __restrict__ qkv,  // [3][N][128]
    int N)
{
    const int nb = blockIdx.x * 64;       // node tile base
    const int cb = blockIdx.y * 64;       // output col tile base in [0,384)
    const float* __restrict__ W = (cb < 128) ? Wq : (cb < 256) ? Wk : Wv;
    const int wrow0 = cb & 127;
    float* __restrict__ outbase = qkv + (size_t)(cb >> 7) * (size_t)N * 128;

    __shared__ float As[64][17];  // +1 pad breaks bank conflicts
    __shared__ float Bs[64][17];

    const int tid = threadIdx.x;
    const int tx = tid & 15;
    const int ty = tid >> 4;

    float acc[4][4] = {};

    const int lrow = tid >> 2;        // 0..63 (tile row for loads)
    const int lk   = (tid & 3) * 4;   // 0,4,8,12
    const int n_load = nb + lrow;

    for (int k0 = 0; k0 < 128; k0 += 16) {
        float4 a = make_float4(0.f, 0.f, 0.f, 0.f);
        if (n_load < N)
            a = *(const float4*)(x + (size_t)n_load * 128 + k0 + lk);
        float4 b = *(const float4*)(W + (size_t)(wrow0 + lrow) * 128 + k0 + lk);
        As[lrow][lk + 0] = a.x; As[lrow][lk + 1] = a.y;
        As[lrow][lk + 2] = a.z; As[lrow][lk + 3] = a.w;
        Bs[lrow][lk + 0] = b.x; Bs[lrow][lk + 1] = b.y;
        Bs[lrow][lk + 2] = b.z; Bs[lrow][lk + 3] = b.w;
        __syncthreads();
#pragma unroll
        for (int kk = 0; kk < 16; ++kk) {
            float av[4], bv[4];
#pragma unroll
            for (int i = 0; i < 4; ++i) av[i] = As[ty * 4 + i][kk];
#pragma unroll
            for (int j = 0; j < 4; ++j) bv[j] = Bs[tx * 4 + j][kk];
#pragma unroll
            for (int i = 0; i < 4; ++i)
#pragma unroll
                for (int j = 0; j < 4; ++j)
                    acc[i][j] = fmaf(av[i], bv[j], acc[i][j]);
        }
        __syncthreads();
    }
#pragma unroll
    for (int i = 0; i < 4; ++i) {
        int n = nb + ty * 4 + i;
        if (n < N) {
            float4 o = make_float4(acc[i][0], acc[i][1], acc[i][2], acc[i][3]);
            *(float4*)(outbase + (size_t)n * 128 + wrow0 + tx * 4) = o;
        }
    }
}

__global__ __launch_bounds__(256) void edge_score_kernel(
    const float* __restrict__ q,
    const float* __restrict__ k,
    const int* __restrict__ edge_index,   // [2][E]: row0=src, row1=dst
    const float* __restrict__ edge_attr,  // [E][32]
    const float* __restrict__ We,         // [8][32]
    float* __restrict__ ex,               // [E][8]
    float* __restrict__ denom,            // [N][8]
    int E)
{
    __shared__ float WeS[256];
    WeS[threadIdx.x] = We[threadIdx.x];
    __syncthreads();

    long long gid = (long long)blockIdx.x * 256 + threadIdx.x;
    long long e = gid >> 3;
    int h = (int)(gid & 7);
    if (e >= E) return;

    int s = edge_index[e];
    int d = edge_index[(size_t)E + e];

    const float4* qp = (const float4*)(q + (size_t)d * 128 + h * 16);
    const float4* kp = (const float4*)(k + (size_t)s * 128 + h * 16);
    float dot = 0.f;
#pragma unroll
    for (int j = 0; j < 4; ++j) {
        float4 qa = qp[j], ka = kp[j];
        dot += qa.x * ka.x + qa.y * ka.y + qa.z * ka.z + qa.w * ka.w;
    }

    const float4* ep = (const float4*)(edge_attr + (size_t)e * 32);
    const float4* wp = (const float4*)(WeS + h * 32);
    float bias = 0.f;
#pragma unroll
    for (int j = 0; j < 8; ++j) {
        float4 ea = ep[j], wa = wp[j];
        bias += ea.x * wa.x + ea.y * wa.y + ea.z * wa.z + ea.w * wa.w;
    }

    float sc = dot * 0.25f + bias;       // 1/sqrt(C)=0.25
    float ev = __expf(sc);
    ex[gid] = ev;
    atomicAdd(&denom[(size_t)d * 8 + h], ev);
}

__global__ __launch_bounds__(256) void edge_out_kernel(
    const float* __restrict__ v,
    const int* __restrict__ edge_index,
    const float* __restrict__ ex,
    const float* __restrict__ denom,
    float* __restrict__ out,              // [N][128]
    int E)
{
    long long gid = (long long)blockIdx.x * 256 + threadIdx.x;
    long long e = gid >> 3;
    int h = (int)(gid & 7);
    if (e >= E) return;

    int s = edge_index[e];
    int d = edge_index[(size_t)E + e];

    float alpha = ex[gid] / denom[(size_t)d * 8 + h];

    const float4* vp = (const float4*)(v + (size_t)s * 128 + h * 16);
    float* op = out + (size_t)d * 128 + h * 16;
#pragma unroll
    for (int j = 0; j < 4; ++j) {
        float4 vv = vp[j];
        atomicAdd(op + j * 4 + 0, alpha * vv.x);
        atomicAdd(op + j * 4 + 1, alpha * vv.y);
        atomicAdd(op + j * 4 + 2, alpha * vv.z);
        atomicAdd(op + j * 4 + 3, alpha * vv.w);
    }
}

extern "C" void kernel_launch(void* const* d_in, const int* in_sizes, int n_in,
                              void* d_out, int out_size, void* d_ws, size_t ws_size,
                              hipStream_t stream) {
    const float* x          = (const float*)d_in[0];
    const int*   edge_index = (const int*)d_in[1];
    const float* edge_attr  = (const float*)d_in[2];
    const float* Wq         = (const float*)d_in[3];
    const float* Wk         = (const float*)d_in[4];
    const float* Wv         = (const float*)d_in[5];
    const float* We         = (const float*)d_in[6];
    float* out = (float*)d_out;

    const int N = in_sizes[0] / 128;
    const int E = in_sizes[1] / 2;

    // Workspace layout (floats): q[N*128] k[N*128] v[N*128] ex[E*8] denom[N*8]
    float* qkv   = (float*)d_ws;
    float* q     = qkv;
    float* k     = qkv + (size_t)N * 128;
    float* v     = qkv + 2 * (size_t)N * 128;
    float* ex    = qkv + 3 * (size_t)N * 128;
    float* denom = ex + (size_t)E * 8;

    hipMemsetAsync(denom, 0, (size_t)N * 8 * sizeof(float), stream);
    hipMemsetAsync(out, 0, (size_t)N * 128 * sizeof(float), stream);

    dim3 g1((N + 63) / 64, 6);
    qkv_gemm_kernel<<<g1, 256, 0, stream>>>(x, Wq, Wk, Wv, qkv, N);

    long long total = (long long)E * 8;
    int blocks = (int)((total + 255) / 256);
    edge_score_kernel<<<blocks, 256, 0, stream>>>(q, k, edge_index, edge_attr,
                                                  We, ex, denom, E);
    edge_out_kernel<<<blocks, 256, 0, stream>>>(v, edge_index, ex, denom, out, E);
}

// Round 2
// 1164.829 us; speedup vs baseline: 10.4681x; 10.4681x over previous
//
#include <hip/hip_runtime.h>

// ---------------------------------------------------------------------------
// Graph multi-head attention conv, fp32, CSR-grouped (no output atomics).
//   N=100000, E=1600000, H=8, C=16, DIM=128, EDGE_DIM=32
// Stages:
//   1) qkv_gemm_kernel : q/k/v = x @ W{q,k,v}^T (tiled fp32 SGEMM)
//   2) CSR build: count[dst]++, single-block scan -> offsets, scatter perm
//   3) attn_fused_kernel: one wave per dst node; per incoming edge compute
//      score (8-lane shuffle reduce), exp, denom & weighted-V accumulate in
//      registers; single coalesced 512B row write. No atomics, no ex array.
// Softmax max-subtraction skipped (alpha invariant; scores are O(10)).
// ---------------------------------------------------------------------------

__global__ __launch_bounds__(256) void qkv_gemm_kernel(
    const float* __restrict__ x,
    const float* __restrict__ Wq,
    const float* __restrict__ Wk,
    const float* __restrict__ Wv,
    float* __restrict__ qkv,  // [3][N][128]
    int N)
{
    const int nb = blockIdx.x * 64;
    const int cb = blockIdx.y * 64;
    const float* __restrict__ W = (cb < 128) ? Wq : (cb < 256) ? Wk : Wv;
    const int wrow0 = cb & 127;
    float* __restrict__ outbase = qkv + (size_t)(cb >> 7) * (size_t)N * 128;

    __shared__ float As[64][17];
    __shared__ float Bs[64][17];

    const int tid = threadIdx.x;
    const int tx = tid & 15;
    const int ty = tid >> 4;

    float acc[4][4] = {};

    const int lrow = tid >> 2;
    const int lk   = (tid & 3) * 4;
    const int n_load = nb + lrow;

    for (int k0 = 0; k0 < 128; k0 += 16) {
        float4 a = make_float4(0.f, 0.f, 0.f, 0.f);
        if (n_load < N)
            a = *(const float4*)(x + (size_t)n_load * 128 + k0 + lk);
        float4 b = *(const float4*)(W + (size_t)(wrow0 + lrow) * 128 + k0 + lk);
        As[lrow][lk + 0] = a.x; As[lrow][lk + 1] = a.y;
        As[lrow][lk + 2] = a.z; As[lrow][lk + 3] = a.w;
        Bs[lrow][lk + 0] = b.x; Bs[lrow][lk + 1] = b.y;
        Bs[lrow][lk + 2] = b.z; Bs[lrow][lk + 3] = b.w;
        __syncthreads();
#pragma unroll
        for (int kk = 0; kk < 16; ++kk) {
            float av[4], bv[4];
#pragma unroll
            for (int i = 0; i < 4; ++i) av[i] = As[ty * 4 + i][kk];
#pragma unroll
            for (int j = 0; j < 4; ++j) bv[j] = Bs[tx * 4 + j][kk];
#pragma unroll
            for (int i = 0; i < 4; ++i)
#pragma unroll
                for (int j = 0; j < 4; ++j)
                    acc[i][j] = fmaf(av[i], bv[j], acc[i][j]);
        }
        __syncthreads();
    }
#pragma unroll
    for (int i = 0; i < 4; ++i) {
        int n = nb + ty * 4 + i;
        if (n < N) {
            float4 o = make_float4(acc[i][0], acc[i][1], acc[i][2], acc[i][3]);
            *(float4*)(outbase + (size_t)n * 128 + wrow0 + tx * 4) = o;
        }
    }
}

__global__ __launch_bounds__(256) void count_kernel(
    const int* __restrict__ edge_index, int* __restrict__ counts, int E)
{
    int e = blockIdx.x * 256 + threadIdx.x;
    if (e < E) atomicAdd(&counts[edge_index[(size_t)E + e]], 1);
}

__global__ __launch_bounds__(1024) void scan_kernel(
    const int* __restrict__ counts,
    int* __restrict__ offsets,
    int* __restrict__ cursor,
    int N)
{
    __shared__ int sums[1024];
    const int t = threadIdx.x;
    const int chunk = (N + 1023) >> 10;
    const int lo = t * chunk;
    const int hi = min(lo + chunk, N);
    int s = 0;
    for (int i = lo; i < hi; ++i) s += counts[i];
    sums[t] = s;
    __syncthreads();
    for (int off = 1; off < 1024; off <<= 1) {
        int tmp = (t >= off) ? sums[t - off] : 0;
        __syncthreads();
        sums[t] += tmp;
        __syncthreads();
    }
    int running = sums[t] - s;  // exclusive base for this chunk
    for (int i = lo; i < hi; ++i) {
        offsets[i] = running;
        cursor[i]  = running;
        running += counts[i];
    }
}

__global__ __launch_bounds__(256) void scatter_kernel(
    const int* __restrict__ edge_index,
    int* __restrict__ cursor,
    int* __restrict__ perm_src,
    int* __restrict__ perm_e,
    int E)
{
    int e = blockIdx.x * 256 + threadIdx.x;
    if (e >= E) return;
    int s = edge_index[e];
    int d = edge_index[(size_t)E + e];
    int pos = atomicAdd(&cursor[d], 1);
    perm_src[pos] = s;
    perm_e[pos]   = e;
}

__global__ __launch_bounds__(256) void attn_fused_kernel(
    const float* __restrict__ q,
    const float* __restrict__ k,
    const float* __restrict__ v,
    const float* __restrict__ edge_attr,  // [E][32]
    const float* __restrict__ We,         // [8][32]
    const int* __restrict__ offsets,
    const int* __restrict__ counts,
    const int* __restrict__ perm_src,
    const int* __restrict__ perm_e,
    float* __restrict__ out,              // [N][128]
    int N)
{
    const int d    = blockIdx.x * 4 + (threadIdx.x >> 6);
    const int lane = threadIdx.x & 63;
    if (d >= N) return;
    const int h = lane >> 3;   // head 0..7
    const int j = lane & 7;    // position within head group

    // Per-lane constants: We chunk and q channels
    const float4 we4 = *(const float4*)(We + h * 32 + j * 4);
    const float2 q2  = *(const float2*)(q + (size_t)d * 128 + lane * 2);

    const int start = offsets[d];
    const int cnt   = counts[d];

    float denom = 0.f;
    float accx = 0.f, accy = 0.f;

    for (int i = start; i < start + cnt; ++i) {
        int src = perm_src[i];
        int e   = perm_e[i];
        float2 k2 = *(const float2*)(k + (size_t)src * 128 + lane * 2);
        float4 ea = *(const float4*)(edge_attr + (size_t)e * 32 + j * 4);
        float part = 0.25f * (q2.x * k2.x + q2.y * k2.y)
                   + ea.x * we4.x + ea.y * we4.y + ea.z * we4.z + ea.w * we4.w;
        part += __shfl_xor(part, 1);
        part += __shfl_xor(part, 2);
        part += __shfl_xor(part, 4);
        float ev = __expf(part);
        denom += ev;
        float2 v2 = *(const float2*)(v + (size_t)src * 128 + lane * 2);
        accx = fmaf(ev, v2.x, accx);
        accy = fmaf(ev, v2.y, accy);
    }

    float inv = denom > 0.f ? 1.f / denom : 0.f;
    float2 o = make_float2(accx * inv, accy * inv);
    *(float2*)(out + (size_t)d * 128 + lane * 2) = o;
}

extern "C" void kernel_launch(void* const* d_in, const int* in_sizes, int n_in,
                              void* d_out, int out_size, void* d_ws, size_t ws_size,
                              hipStream_t stream) {
    const float* x          = (const float*)d_in[0];
    const int*   edge_index = (const int*)d_in[1];
    const float* edge_attr  = (const float*)d_in[2];
    const float* Wq         = (const float*)d_in[3];
    const float* Wk         = (const float*)d_in[4];
    const float* Wv         = (const float*)d_in[5];
    const float* We         = (const float*)d_in[6];
    float* out = (float*)d_out;

    const int N = in_sizes[0] / 128;
    const int E = in_sizes[1] / 2;

    // Workspace layout: qkv[3*N*128] f32 | counts,offsets,cursor[N] i32 |
    //                   perm_src,perm_e[E] i32   (~168 MB total)
    float* qkv = (float*)d_ws;
    float* q = qkv;
    float* k = qkv + (size_t)N * 128;
    float* v = qkv + 2 * (size_t)N * 128;
    int* counts   = (int*)(qkv + 3 * (size_t)N * 128);
    int* offsets  = counts + N;
    int* cursor   = offsets + N;
    int* perm_src = cursor + N;
    int* perm_e   = perm_src + E;

    hipMemsetAsync(counts, 0, (size_t)N * sizeof(int), stream);

    dim3 g1((N + 63) / 64, 6);
    qkv_gemm_kernel<<<g1, 256, 0, stream>>>(x, Wq, Wk, Wv, qkv, N);

    int eblocks = (E + 255) / 256;
    count_kernel<<<eblocks, 256, 0, stream>>>(edge_index, counts, E);
    scan_kernel<<<1, 1024, 0, stream>>>(counts, offsets, cursor, N);
    scatter_kernel<<<eblocks, 256, 0, stream>>>(edge_index, cursor,
                                                perm_src, perm_e, E);

    attn_fused_kernel<<<(N + 3) / 4, 256, 0, stream>>>(
        q, k, v, edge_attr, We, offsets, counts, perm_src, perm_e, out, N);
}

// Round 3
// 769.209 us; speedup vs baseline: 15.8520x; 1.5143x over previous
//
#include <hip/hip_runtime.h>

// ---------------------------------------------------------------------------
// Graph multi-head attention conv, CSR-grouped, bf16 k/v.
//   N=100000, E=1600000, H=8, C=16, DIM=128, EDGE_DIM=32
// Stages:
//   1) qkv_count_kernel: grid (nb,7). y<6: tiled fp32 SGEMM (transposed-LDS,
//      ds_read_b128 fragments); q stored fp32, k/v stored bf16 in epilogue.
//      y==6: dst-degree histogram (int4 loads + L2 atomics) — hides under GEMM.
//   2) 3-kernel hierarchical exclusive scan -> offsets/cursor.
//   3) scatter: perm[pos] = int2(src, e)  (8B packed writes).
//   4) attn_fused: one wave per dst; perm batch-loaded + __shfl broadcast,
//      next-edge k/v/ea prefetched before the shuffle-reduce; bf16 k/v;
//      single coalesced 512B row write. No atomics in the hot path.
// Softmax max-subtraction skipped (alpha invariant; scores O(10)).
// ---------------------------------------------------------------------------

typedef unsigned int uint32;
typedef unsigned short ushort16;

__device__ inline unsigned short f2bf(float f) {  // round-to-nearest-even
    uint32 u = __float_as_uint(f);
    uint32 r = u + 0x7fffu + ((u >> 16) & 1u);
    return (unsigned short)(r >> 16);
}

__global__ __launch_bounds__(256) void qkv_count_kernel(
    const float* __restrict__ x,
    const float* __restrict__ Wq,
    const float* __restrict__ Wk,
    const float* __restrict__ Wv,
    const int* __restrict__ edge_index,
    float* __restrict__ q,            // [N][128] fp32
    unsigned short* __restrict__ kbf, // [N][128] bf16
    unsigned short* __restrict__ vbf, // [N][128] bf16
    int* __restrict__ counts,
    int N, int E)
{
    if (blockIdx.y == 6) {
        // ---- degree histogram, 4 edges/thread ----
        int idx = blockIdx.x * 256 + threadIdx.x;
        if (idx * 4 + 3 < E) {
            int4 d4 = ((const int4*)(edge_index + E))[idx];
            atomicAdd(&counts[d4.x], 1);
            atomicAdd(&counts[d4.y], 1);
            atomicAdd(&counts[d4.z], 1);
            atomicAdd(&counts[d4.w], 1);
        } else {
            for (int e = idx * 4; e < E; ++e)
                atomicAdd(&counts[edge_index[(size_t)E + e]], 1);
        }
        return;
    }

    const int nb = blockIdx.x * 64;
    const int cb = blockIdx.y * 64;
    const float* __restrict__ W = (cb < 128) ? Wq : (cb < 256) ? Wk : Wv;
    const int wrow0 = cb & 127;

    // transposed tiles: [kk][row], pad 68 keeps 16B alignment, conflicts <=2-way
    __shared__ float As[16][68];
    __shared__ float Bs[16][68];

    const int tid = threadIdx.x;
    const int tx = tid & 15;
    const int ty = tid >> 4;

    float acc[4][4] = {};

    const int lrow = tid >> 2;
    const int lk   = (tid & 3) * 4;
    const int n_load = nb + lrow;

    for (int k0 = 0; k0 < 128; k0 += 16) {
        float4 a = make_float4(0.f, 0.f, 0.f, 0.f);
        if (n_load < N)
            a = *(const float4*)(x + (size_t)n_load * 128 + k0 + lk);
        float4 b = *(const float4*)(W + (size_t)(wrow0 + lrow) * 128 + k0 + lk);
        As[lk + 0][lrow] = a.x; As[lk + 1][lrow] = a.y;
        As[lk + 2][lrow] = a.z; As[lk + 3][lrow] = a.w;
        Bs[lk + 0][lrow] = b.x; Bs[lk + 1][lrow] = b.y;
        Bs[lk + 2][lrow] = b.z; Bs[lk + 3][lrow] = b.w;
        __syncthreads();
#pragma unroll
        for (int kk = 0; kk < 16; ++kk) {
            float4 av = *(const float4*)&As[kk][ty * 4];
            float4 bv = *(const float4*)&Bs[kk][tx * 4];
            float avr[4] = {av.x, av.y, av.z, av.w};
            float bvr[4] = {bv.x, bv.y, bv.z, bv.w};
#pragma unroll
            for (int i = 0; i < 4; ++i)
#pragma unroll
                for (int j = 0; j < 4; ++j)
                    acc[i][j] = fmaf(avr[i], bvr[j], acc[i][j]);
        }
        __syncthreads();
    }

#pragma unroll
    for (int i = 0; i < 4; ++i) {
        int n = nb + ty * 4 + i;
        if (n >= N) continue;
        if (cb < 128) {
            float4 o = make_float4(acc[i][0], acc[i][1], acc[i][2], acc[i][3]);
            *(float4*)(q + (size_t)n * 128 + wrow0 + tx * 4) = o;
        } else {
            unsigned short* kv = (cb < 256) ? kbf : vbf;
            ushort4 o;
            o.x = f2bf(acc[i][0]); o.y = f2bf(acc[i][1]);
            o.z = f2bf(acc[i][2]); o.w = f2bf(acc[i][3]);
            *(ushort4*)(kv + (size_t)n * 128 + wrow0 + tx * 4) = o;
        }
    }
}

__global__ __launch_bounds__(256) void scan_pass1(
    const int* __restrict__ counts, int* __restrict__ blocksums, int N)
{
    __shared__ int red[256];
    int base = blockIdx.x * 512;
    int t = threadIdx.x;
    int s = 0;
    if (base + t < N)       s += counts[base + t];
    if (base + 256 + t < N) s += counts[base + 256 + t];
    red[t] = s;
    __syncthreads();
    for (int off = 128; off > 0; off >>= 1) {
        if (t < off) red[t] += red[t + off];
        __syncthreads();
    }
    if (t == 0) blocksums[blockIdx.x] = red[0];
}

__global__ __launch_bounds__(256) void scan_pass2(
    const int* __restrict__ blocksums, int* __restrict__ blockbase, int NB)
{
    __shared__ int sc[256];
    int t = threadIdx.x;
    int v = (t < NB) ? blocksums[t] : 0;
    sc[t] = v;
    __syncthreads();
    for (int off = 1; off < 256; off <<= 1) {
        int tmp = (t >= off) ? sc[t - off] : 0;
        __syncthreads();
        sc[t] += tmp;
        __syncthreads();
    }
    if (t < NB) blockbase[t] = sc[t] - v;  // exclusive
}

__global__ __launch_bounds__(256) void scan_pass3(
    const int* __restrict__ counts, const int* __restrict__ blockbase,
    int* __restrict__ offsets, int* __restrict__ cursor, int N)
{
    __shared__ int sc[256];
    int base = blockIdx.x * 512;
    int t = threadIdx.x;
    int i0 = base + 2 * t, i1 = i0 + 1;
    int c0 = (i0 < N) ? counts[i0] : 0;
    int c1 = (i1 < N) ? counts[i1] : 0;
    int pair = c0 + c1;
    sc[t] = pair;
    __syncthreads();
    for (int off = 1; off < 256; off <<= 1) {
        int tmp = (t >= off) ? sc[t - off] : 0;
        __syncthreads();
        sc[t] += tmp;
        __syncthreads();
    }
    int ex = sc[t] - pair + blockbase[blockIdx.x];
    if (i0 < N) { offsets[i0] = ex;      cursor[i0] = ex; }
    if (i1 < N) { offsets[i1] = ex + c0; cursor[i1] = ex + c0; }
}

__global__ __launch_bounds__(256) void scatter_kernel(
    const int* __restrict__ edge_index,
    int* __restrict__ cursor,
    int2* __restrict__ perm,
    int E)
{
    int e = blockIdx.x * 256 + threadIdx.x;
    if (e >= E) return;
    int s = edge_index[e];
    int d = edge_index[(size_t)E + e];
    int pos = atomicAdd(&cursor[d], 1);
    perm[pos] = make_int2(s, e);
}

__global__ __launch_bounds__(256) void attn_fused_kernel(
    const float* __restrict__ q,
    const unsigned short* __restrict__ kbf,
    const unsigned short* __restrict__ vbf,
    const float* __restrict__ edge_attr,  // [E][32]
    const float* __restrict__ We,         // [8][32]
    const int* __restrict__ offsets,
    const int* __restrict__ counts,
    const int2* __restrict__ perm,
    float* __restrict__ out,              // [N][128]
    int N)
{
    const int d    = blockIdx.x * 4 + (threadIdx.x >> 6);
    const int lane = threadIdx.x & 63;
    if (d >= N) return;
    const int h = lane >> 3;
    const int j = lane & 7;

    const float4 we4 = *(const float4*)(We + h * 32 + j * 4);
    const float2 q2  = *(const float2*)(q + (size_t)d * 128 + lane * 2);

    const int start = offsets[d];
    const int cnt   = counts[d];

    float denom = 0.f, accx = 0.f, accy = 0.f;

    for (int i0 = 0; i0 < cnt; i0 += 64) {
        int m = min(64, cnt - i0);
        int2 pv = make_int2(0, 0);
        if (lane < m) pv = perm[start + i0 + lane];

        // prefetch edge 0
        int src = __shfl(pv.x, 0), e = __shfl(pv.y, 0);
        uint32 kk2 = *(const uint32*)(kbf + (size_t)src * 128 + lane * 2);
        uint32 vv2 = *(const uint32*)(vbf + (size_t)src * 128 + lane * 2);
        float4 ea  = *(const float4*)(edge_attr + (size_t)e * 32 + j * 4);

        for (int t = 0; t < m; ++t) {
            uint32 ck = kk2, cv = vv2;
            float4 cea = ea;
            if (t + 1 < m) {
                int ns = __shfl(pv.x, t + 1), ne = __shfl(pv.y, t + 1);
                kk2 = *(const uint32*)(kbf + (size_t)ns * 128 + lane * 2);
                vv2 = *(const uint32*)(vbf + (size_t)ns * 128 + lane * 2);
                ea  = *(const float4*)(edge_attr + (size_t)ne * 32 + j * 4);
            }
            float kx = __uint_as_float(ck << 16);
            float ky = __uint_as_float(ck & 0xffff0000u);
            float part = 0.25f * (q2.x * kx + q2.y * ky)
                       + cea.x * we4.x + cea.y * we4.y
                       + cea.z * we4.z + cea.w * we4.w;
            part += __shfl_xor(part, 1);
            part += __shfl_xor(part, 2);
            part += __shfl_xor(part, 4);
            float ev = __expf(part);
            denom += ev;
            float vx = __uint_as_float(cv << 16);
            float vy = __uint_as_float(cv & 0xffff0000u);
            accx = fmaf(ev, vx, accx);
            accy = fmaf(ev, vy, accy);
        }
    }

    float inv = denom > 0.f ? 1.f / denom : 0.f;
    *(float2*)(out + (size_t)d * 128 + lane * 2) = make_float2(accx * inv, accy * inv);
}

extern "C" void kernel_launch(void* const* d_in, const int* in_sizes, int n_in,
                              void* d_out, int out_size, void* d_ws, size_t ws_size,
                              hipStream_t stream) {
    const float* x          = (const float*)d_in[0];
    const int*   edge_index = (const int*)d_in[1];
    const float* edge_attr  = (const float*)d_in[2];
    const float* Wq         = (const float*)d_in[3];
    const float* Wk         = (const float*)d_in[4];
    const float* Wv         = (const float*)d_in[5];
    const float* We         = (const float*)d_in[6];
    float* out = (float*)d_out;

    const int N = in_sizes[0] / 128;
    const int E = in_sizes[1] / 2;

    // ws layout: q f32[N*128] | kbf,vbf bf16[N*128] | perm int2[E] |
    //            counts,offsets,cursor[N] | blocksums,blockbase[256]
    float* q = (float*)d_ws;
    unsigned short* kbf = (unsigned short*)(q + (size_t)N * 128);
    unsigned short* vbf = kbf + (size_t)N * 128;
    int2* perm = (int2*)(vbf + (size_t)N * 128);
    int* counts    = (int*)(perm + E);
    int* offsets   = counts + N;
    int* cursor    = offsets + N;
    int* blocksums = cursor + N;
    int* blockbase = blocksums + 256;

    hipMemsetAsync(counts, 0, (size_t)N * sizeof(int), stream);

    const int nxb = (N + 63) / 64;  // 1563
    dim3 g1(nxb, 7);                // y<6: GEMM, y==6: histogram
    qkv_count_kernel<<<g1, 256, 0, stream>>>(x, Wq, Wk, Wv, edge_index,
                                             q, kbf, vbf, counts, N, E);

    const int NB = (N + 511) / 512;  // 196
    scan_pass1<<<NB, 256, 0, stream>>>(counts, blocksums, N);
    scan_pass2<<<1, 256, 0, stream>>>(blocksums, blockbase, NB);
    scan_pass3<<<NB, 256, 0, stream>>>(counts, blockbase, offsets, cursor, N);

    scatter_kernel<<<(E + 255) / 256, 256, 0, stream>>>(edge_index, cursor,
                                                        perm, E);

    attn_fused_kernel<<<(N + 3) / 4, 256, 0, stream>>>(
        q, kbf, vbf, edge_attr, We, offsets, counts, perm, out, N);
}